// Round 2
// baseline (886.745 us; speedup 1.0000x reference)
//
#include <hip/hip_runtime.h>
#include <stdint.h>

#define BN 16384
#define DD 1024
#define HH 256
#define EE 8

typedef __attribute__((ext_vector_type(8))) short short8;
typedef __attribute__((ext_vector_type(4))) float floatx4;

__device__ __forceinline__ unsigned short f2bf(float f) {
  union { float f; unsigned int i; } v; v.f = f;
  unsigned int x = v.i;
  x += 0x7fffu + ((x >> 16) & 1u);  // RTNE
  return (unsigned short)(x >> 16);
}
__device__ __forceinline__ float bf2f(unsigned short u) {
  union { unsigned int i; float f; } v; v.i = ((unsigned int)u) << 16; return v.f;
}
__device__ __forceinline__ unsigned int pack2(float a, float b) {
  return (unsigned int)f2bf(a) | ((unsigned int)f2bf(b) << 16);
}

// ---------------- gating: fp32 logits -> top2 -> weights + group histogram ----------------
__global__ __launch_bounds__(256) void gating_kernel(
    const float* __restrict__ x,
    const float* __restrict__ gate_w,
    const float* __restrict__ gate_b,
    int* __restrict__ rinfo_e, float* __restrict__ rinfo_w,
    int* __restrict__ cnt) {
  __shared__ float gw[DD * EE];  // 32 KB
  int tid = threadIdx.x;
  for (int i = tid; i < DD * EE / 4; i += 256)
    ((float4*)gw)[i] = ((const float4*)gate_w)[i];
  __syncthreads();
  int lane = tid & 63;
  int row = blockIdx.x * 4 + (tid >> 6);
  const float* xr = x + (size_t)row * DD;
  float acc[EE];
#pragma unroll
  for (int e = 0; e < EE; e++) acc[e] = 0.f;
#pragma unroll
  for (int i = 0; i < DD / 64; i++) {
    int d = lane + i * 64;
    float xv = xr[d];
    float4 g0 = *(const float4*)&gw[d * 8];
    float4 g1 = *(const float4*)&gw[d * 8 + 4];
    acc[0] += xv * g0.x; acc[1] += xv * g0.y;
    acc[2] += xv * g0.z; acc[3] += xv * g0.w;
    acc[4] += xv * g1.x; acc[5] += xv * g1.y;
    acc[6] += xv * g1.z; acc[7] += xv * g1.w;
  }
#pragma unroll
  for (int s = 1; s < 64; s <<= 1) {
#pragma unroll
    for (int e = 0; e < EE; e++) acc[e] += __shfl_xor(acc[e], s, 64);
  }
  if (lane == 0) {
    float lg[EE];
#pragma unroll
    for (int e = 0; e < EE; e++) lg[e] = acc[e] + gate_b[e];
    int i1 = 0;
    for (int e = 1; e < EE; e++) if (lg[e] > lg[i1]) i1 = e;
    int i2 = (i1 == 0) ? 1 : 0;
    for (int e = 0; e < EE; e++) if (e != i1 && lg[e] > lg[i2]) i2 = e;
    float wA = 1.f / (1.f + __expf(lg[i2] - lg[i1]));  // p1/(p1+p2), exp arg <= 0
    float wB = 1.f - wA;
    rinfo_e[row] = i1 | (i2 << 8);
    rinfo_w[row * 2 + 0] = wA;
    rinfo_w[row * 2 + 1] = wB;
    atomicAdd(&cnt[i1], 1);
    atomicAdd(&cnt[8 + i2], 1);
  }
}

// cnt[0..15]=counts, cnt[16..31]=cursors(zeroed), cnt[32..47]=offsets
__global__ void scan_kernel(int* cnt) {
  if (threadIdx.x == 0) {
    int s = 0;
    for (int g = 0; g < 16; g++) { cnt[32 + g] = s; s += cnt[g]; }
  }
}

__global__ __launch_bounds__(256) void scatter_kernel(
    const int* __restrict__ rinfo_e, const float* __restrict__ rinfo_w,
    int* cnt, int* __restrict__ rowidx, float* __restrict__ wgt) {
  int row = blockIdx.x * 256 + threadIdx.x;
  int ee = rinfo_e[row];
  int e0 = ee & 255, e1 = (ee >> 8) & 255;
  int* curs = cnt + 16;
  const int* offs = cnt + 32;
  int p0 = offs[e0] + atomicAdd(&curs[e0], 1);
  rowidx[p0] = row; wgt[p0] = rinfo_w[row * 2 + 0];
  int p1 = offs[8 + e1] + atomicAdd(&curs[8 + e1], 1);
  rowidx[p1] = row; wgt[p1] = rinfo_w[row * 2 + 1];
}

// src fp32 [E][R][C] -> dst bf16 [E][C][R]
__global__ void transpose_kernel(const float* __restrict__ src,
                                 unsigned short* __restrict__ dst, int R, int C) {
  __shared__ float tbuf[32][33];
  int e = blockIdx.z;
  int c0 = blockIdx.x * 32, r0 = blockIdx.y * 32;
  int tx = threadIdx.x, ty = threadIdx.y;
  const float* s = src + (size_t)e * R * C;
  unsigned short* d = dst + (size_t)e * R * C;
  for (int yy = ty; yy < 32; yy += 8)
    tbuf[yy][tx] = s[(size_t)(r0 + yy) * C + c0 + tx];
  __syncthreads();
  for (int yy = ty; yy < 32; yy += 8)
    d[(size_t)(c0 + yy) * R + r0 + tx] = f2bf(tbuf[tx][yy]);
}

// ---------------- grouped GEMM1: h = gelu(Xg @ w1[e] + b1[e]) ----------------
// 128x128 tile, 4 waves (2x2), each wave 64x64 via 4x4 mfma_f32_16x16x32_bf16
__global__ __launch_bounds__(256) void gemm1_kernel(
    const float* __restrict__ x,
    const unsigned short* __restrict__ w1t,   // [E][H][D] bf16
    const float* __restrict__ b1,             // [E][H] fp32
    const int* __restrict__ cnt,
    const int* __restrict__ rowidx,
    unsigned short* __restrict__ hbuf,        // [16384][256] bf16 (per phase)
    int phase) {
  __shared__ unsigned short As[128][72];
  __shared__ unsigned short Bs[128][72];
  int t = blockIdx.x, g = -1, lt = 0;
#pragma unroll 1
  for (int gg = 0; gg < 8; gg++) {
    int G = phase * 8 + gg;
    int nt = (cnt[G] + 127) >> 7;
    if (t < nt) { g = G; lt = t; break; }
    t -= nt;
  }
  if (g < 0) return;
  const int* offs = cnt + 32;
  int m0 = offs[g] + lt * 128;
  int mEnd = offs[g] + cnt[g];
  int e = g & 7;
  int n0 = blockIdx.y * 128;
  const unsigned short* Bsrc = w1t + (size_t)e * HH * DD + (size_t)n0 * DD;
  int tid = threadIdx.x, lane = tid & 63, wv = tid >> 6;
  int wr = (wv >> 1) * 64, wc = (wv & 1) * 64;
  int lm = lane & 15, q = lane >> 4;
  floatx4 acc[4][4];
  floatx4 zero = {0.f, 0.f, 0.f, 0.f};
#pragma unroll
  for (int i = 0; i < 4; i++)
#pragma unroll
    for (int j = 0; j < 4; j++) acc[i][j] = zero;
  int sr = tid >> 3;
  int sc = (tid & 7) * 8;
  int grows[4];
#pragma unroll
  for (int it = 0; it < 4; it++) {
    int pos = m0 + it * 32 + sr;
    grows[it] = (pos < mEnd) ? rowidx[pos] : -1;
  }
#pragma unroll 1
  for (int k0 = 0; k0 < DD; k0 += 64) {
#pragma unroll
    for (int it = 0; it < 4; it++) {
      int r = it * 32 + sr;
      uint4 av = {0u, 0u, 0u, 0u};
      if (grows[it] >= 0) {
        const float* srcp = x + (size_t)grows[it] * DD + k0 + sc;
        float4 f0 = *(const float4*)srcp;
        float4 f1 = *(const float4*)(srcp + 4);
        av.x = pack2(f0.x, f0.y); av.y = pack2(f0.z, f0.w);
        av.z = pack2(f1.x, f1.y); av.w = pack2(f1.z, f1.w);
      }
      *(uint4*)&As[r][sc] = av;
      *(uint4*)&Bs[r][sc] = *(const uint4*)(Bsrc + (size_t)r * DD + k0 + sc);
    }
    __syncthreads();
#pragma unroll
    for (int ks = 0; ks < 2; ks++) {
      short8 a[4], b[4];
#pragma unroll
      for (int i = 0; i < 4; i++)
        a[i] = *(const short8*)&As[wr + i * 16 + lm][ks * 32 + q * 8];
#pragma unroll
      for (int j = 0; j < 4; j++)
        b[j] = *(const short8*)&Bs[wc + j * 16 + lm][ks * 32 + q * 8];
#pragma unroll
      for (int i = 0; i < 4; i++)
#pragma unroll
        for (int j = 0; j < 4; j++)
          acc[i][j] = __builtin_amdgcn_mfma_f32_16x16x32_bf16(a[i], b[j], acc[i][j], 0, 0, 0);
    }
    __syncthreads();
  }
  int hbase = phase * 16384;
#pragma unroll
  for (int i = 0; i < 4; i++) {
#pragma unroll
    for (int r = 0; r < 4; r++) {
      int row = wr + i * 16 + q * 4 + r;
      int pos = m0 + row;
      if (pos < mEnd) {
#pragma unroll
        for (int j = 0; j < 4; j++) {
          int col = n0 + wc + j * 16 + lm;
          float v = acc[i][j][r] + b1[e * HH + col];
          v = 0.5f * v * (1.f + erff(v * 0.70710678118654752f));  // exact GELU
          hbuf[(size_t)(pos - hbase) * HH + col] = f2bf(v);
        }
      }
    }
  }
}

// ---------------- grouped GEMM2: out (+)= w * (h @ w2[e] + b2[e]) ----------------
// phase 0: top-1 groups, direct fp32 write. phase 1: top-2 groups, read-add-write.
__global__ __launch_bounds__(256) void gemm2_kernel(
    const unsigned short* __restrict__ hbuf,  // [16384][256] bf16
    const unsigned short* __restrict__ w2t,   // [E][D][H] bf16
    const float* __restrict__ b2,             // [E][D] fp32
    const int* __restrict__ cnt,
    const int* __restrict__ rowidx,
    const float* __restrict__ wgt,
    float* __restrict__ out,
    int phase) {
  __shared__ unsigned short As[128][72];
  __shared__ unsigned short Bs[128][72];
  int t = blockIdx.x, g = -1, lt = 0;
#pragma unroll 1
  for (int gg = 0; gg < 8; gg++) {
    int G = phase * 8 + gg;
    int nt = (cnt[G] + 127) >> 7;
    if (t < nt) { g = G; lt = t; break; }
    t -= nt;
  }
  if (g < 0) return;
  const int* offs = cnt + 32;
  int m0 = offs[g] + lt * 128;
  int mEnd = offs[g] + cnt[g];
  int e = g & 7;
  int n0 = blockIdx.y * 128;
  const unsigned short* Bsrc = w2t + (size_t)e * DD * HH + (size_t)n0 * HH;
  int tid = threadIdx.x, lane = tid & 63, wv = tid >> 6;
  int wr = (wv >> 1) * 64, wc = (wv & 1) * 64;
  int lm = lane & 15, q = lane >> 4;
  floatx4 acc[4][4];
  floatx4 zero = {0.f, 0.f, 0.f, 0.f};
#pragma unroll
  for (int i = 0; i < 4; i++)
#pragma unroll
    for (int j = 0; j < 4; j++) acc[i][j] = zero;
  int sr = tid >> 3;
  int sc = (tid & 7) * 8;
  int hbase = phase * 16384;
#pragma unroll 1
  for (int k0 = 0; k0 < HH; k0 += 64) {
#pragma unroll
    for (int it = 0; it < 4; it++) {
      int r = it * 32 + sr;
      int pos = m0 + r;
      uint4 av = {0u, 0u, 0u, 0u};
      if (pos < mEnd)
        av = *(const uint4*)(hbuf + (size_t)(pos - hbase) * HH + k0 + sc);
      *(uint4*)&As[r][sc] = av;
      *(uint4*)&Bs[r][sc] = *(const uint4*)(Bsrc + (size_t)r * HH + k0 + sc);
    }
    __syncthreads();
#pragma unroll
    for (int ks = 0; ks < 2; ks++) {
      short8 a[4], b[4];
#pragma unroll
      for (int i = 0; i < 4; i++)
        a[i] = *(const short8*)&As[wr + i * 16 + lm][ks * 32 + q * 8];
#pragma unroll
      for (int j = 0; j < 4; j++)
        b[j] = *(const short8*)&Bs[wc + j * 16 + lm][ks * 32 + q * 8];
#pragma unroll
      for (int i = 0; i < 4; i++)
#pragma unroll
        for (int j = 0; j < 4; j++)
          acc[i][j] = __builtin_amdgcn_mfma_f32_16x16x32_bf16(a[i], b[j], acc[i][j], 0, 0, 0);
    }
    __syncthreads();
  }
#pragma unroll
  for (int i = 0; i < 4; i++) {
#pragma unroll
    for (int r = 0; r < 4; r++) {
      int row = wr + i * 16 + q * 4 + r;
      int pos = m0 + row;
      if (pos < mEnd) {
        int grow = rowidx[pos];
        float wgain = wgt[pos];
#pragma unroll
        for (int j = 0; j < 4; j++) {
          int col = n0 + wc + j * 16 + lm;
          float v = (acc[i][j][r] + b2[e * DD + col]) * wgain;
          size_t oidx = (size_t)grow * DD + col;
          if (phase) v += out[oidx];
          out[oidx] = v;
        }
      }
    }
  }
}

extern "C" void kernel_launch(void* const* d_in, const int* in_sizes, int n_in,
                              void* d_out, int out_size, void* d_ws, size_t ws_size,
                              hipStream_t stream) {
  (void)in_sizes; (void)n_in; (void)out_size; (void)ws_size;
  const float* x      = (const float*)d_in[0];
  const float* gate_w = (const float*)d_in[1];
  const float* gate_b = (const float*)d_in[2];
  const float* w1     = (const float*)d_in[3];
  const float* b1     = (const float*)d_in[4];
  const float* w2     = (const float*)d_in[5];
  const float* b2     = (const float*)d_in[6];
  float* out = (float*)d_out;

  char* w = (char*)d_ws;
  int* cnt            = (int*)w;                         // [48]: cnt, curs, offs
  int* rinfo_e        = (int*)(w + 256);                 // [16384]
  float* rinfo_w      = (float*)(w + 256 + 65536);       // [32768]
  int* rowidx         = (int*)(w + 196864);              // [32768]
  float* wgt          = (float*)(w + 327936);            // [32768]
  unsigned short* w1t = (unsigned short*)(w + 459008);            // 4 MB bf16
  unsigned short* w2t = (unsigned short*)(w + 459008 + 4194304);  // 4 MB bf16
  unsigned short* hbuf= (unsigned short*)(w + 459008 + 8388608);  // 8 MB bf16 (per-phase)

  hipMemsetAsync(cnt, 0, 128, stream);  // counts + cursors
  transpose_kernel<<<dim3(HH / 32, DD / 32, EE), dim3(32, 8), 0, stream>>>(w1, w1t, DD, HH);
  transpose_kernel<<<dim3(DD / 32, HH / 32, EE), dim3(32, 8), 0, stream>>>(w2, w2t, HH, DD);
  gating_kernel<<<BN / 4, 256, 0, stream>>>(x, gate_w, gate_b, rinfo_e, rinfo_w, cnt);
  scan_kernel<<<1, 64, 0, stream>>>(cnt);
  scatter_kernel<<<BN / 256, 256, 0, stream>>>(rinfo_e, rinfo_w, cnt, rowidx, wgt);
  // phase 0 (top-1 groups), then phase 1 (top-2 groups); hbuf reused
  gemm1_kernel<<<dim3(136, 2), 256, 0, stream>>>(x, w1t, b1, cnt, rowidx, hbuf, 0);
  gemm2_kernel<<<dim3(136, 8), 256, 0, stream>>>(hbuf, w2t, b2, cnt, rowidx, wgt, out, 0);
  gemm1_kernel<<<dim3(136, 2), 256, 0, stream>>>(x, w1t, b1, cnt, rowidx, hbuf, 1);
  gemm2_kernel<<<dim3(136, 8), 256, 0, stream>>>(hbuf, w2t, b2, cnt, rowidx, wgt, out, 1);
}

// Round 3
// 434.542 us; speedup vs baseline: 2.0406x; 2.0406x over previous
//
#include <hip/hip_runtime.h>
#include <stdint.h>

#define BN 16384
#define DD 1024
#define HH 256
#define EE 8
#define GB 512   // gating blocks
#define GR 32    // rows per gating block

typedef __attribute__((ext_vector_type(8))) short short8;
typedef __attribute__((ext_vector_type(4))) float floatx4;

__device__ __forceinline__ unsigned short f2bf(float f) {
  union { float f; unsigned int i; } v; v.f = f;
  unsigned int x = v.i;
  x += 0x7fffu + ((x >> 16) & 1u);  // RTNE
  return (unsigned short)(x >> 16);
}
__device__ __forceinline__ unsigned int pack2(float a, float b) {
  return (unsigned int)f2bf(a) | ((unsigned int)f2bf(b) << 16);
}

// ---------------- gating: fp32 logits -> top2 -> rinfo + per-block histogram ----------------
// No global atomics. gate_w (32 KB) read straight from global (L1-resident).
__global__ __launch_bounds__(256) void gating_kernel(
    const float* __restrict__ x,
    const float* __restrict__ gate_w,
    const float* __restrict__ gate_b,
    int* __restrict__ rinfo_e, float* __restrict__ rinfo_w,
    int* __restrict__ bhist) {
  __shared__ int hist[16];
  int tid = threadIdx.x;
  if (tid < 16) hist[tid] = 0;
  __syncthreads();
  int lane = tid & 63, wv = tid >> 6;
#pragma unroll 1
  for (int it = 0; it < GR / 4; it++) {
    int row = blockIdx.x * GR + it * 4 + wv;
    const float* xr = x + (size_t)row * DD;
    float acc[EE];
#pragma unroll
    for (int e = 0; e < EE; e++) acc[e] = 0.f;
#pragma unroll 4
    for (int i = 0; i < DD / 64; i++) {
      int d = lane + i * 64;
      float xv = xr[d];
      float4 g0 = *(const float4*)&gate_w[d * 8];
      float4 g1 = *(const float4*)&gate_w[d * 8 + 4];
      acc[0] += xv * g0.x; acc[1] += xv * g0.y;
      acc[2] += xv * g0.z; acc[3] += xv * g0.w;
      acc[4] += xv * g1.x; acc[5] += xv * g1.y;
      acc[6] += xv * g1.z; acc[7] += xv * g1.w;
    }
#pragma unroll
    for (int s = 1; s < 64; s <<= 1) {
#pragma unroll
      for (int e = 0; e < EE; e++) acc[e] += __shfl_xor(acc[e], s, 64);
    }
    if (lane == 0) {
      float lg[EE];
#pragma unroll
      for (int e = 0; e < EE; e++) lg[e] = acc[e] + gate_b[e];
      int i1 = 0;
      for (int e = 1; e < EE; e++) if (lg[e] > lg[i1]) i1 = e;
      int i2 = (i1 == 0) ? 1 : 0;
      for (int e = 0; e < EE; e++) if (e != i1 && lg[e] > lg[i2]) i2 = e;
      float wA = 1.f / (1.f + __expf(lg[i2] - lg[i1]));  // p1/(p1+p2), arg <= 0
      float wB = 1.f - wA;
      rinfo_e[row] = i1 | (i2 << 8);
      rinfo_w[row * 2 + 0] = wA;
      rinfo_w[row * 2 + 1] = wB;
      atomicAdd(&hist[i1], 1);      // LDS atomics only
      atomicAdd(&hist[8 + i2], 1);
    }
  }
  __syncthreads();
  if (tid < 16) bhist[blockIdx.x * 16 + tid] = hist[tid];
}

// ---------------- scan: totals, group offsets, per-block bases (deterministic) ----------------
// cnt[0..15]=counts, cnt[32..47]=group offsets. bbase[b][g] = global slot base for block b.
__global__ __launch_bounds__(256) void scan_kernel(
    const int* __restrict__ bhist, int* __restrict__ cnt, int* __restrict__ bbase) {
  __shared__ int cs[16][16];  // [chunk][group], chunk = 32 gating blocks
  __shared__ int ofs[16];
  int tid = threadIdx.x;
  int g = tid & 15, c = tid >> 4;
  int s = 0;
#pragma unroll 1
  for (int b = c * 32; b < c * 32 + 32; b++) s += bhist[b * 16 + g];
  cs[c][g] = s;
  __syncthreads();
  if (tid == 0) {
    int run = 0;
    for (int gg = 0; gg < 16; gg++) {
      int tot = 0;
      for (int cc = 0; cc < 16; cc++) tot += cs[cc][gg];
      cnt[gg] = tot;
      cnt[16 + gg] = 0;
      cnt[32 + gg] = run;
      ofs[gg] = run;
      run += tot;
    }
  }
  __syncthreads();
  if (tid < 16) {  // tid = group
    int run = ofs[tid];
#pragma unroll 1
    for (int cc = 0; cc < 16; cc++) { int t = cs[cc][tid]; cs[cc][tid] = run; run += t; }
  }
  __syncthreads();
  int run = cs[c][g];
#pragma unroll 1
  for (int b = c * 32; b < c * 32 + 32; b++) {
    bbase[b * 16 + g] = run;
    run += bhist[b * 16 + g];
  }
}

// ---------------- scatter: rank rows within block via LDS cursors ----------------
__global__ __launch_bounds__(64) void scatter_kernel(
    const int* __restrict__ rinfo_e, const float* __restrict__ rinfo_w,
    const int* __restrict__ bbase,
    int* __restrict__ rowidx, float* __restrict__ wgt) {
  __shared__ int curs[16];
  int tid = threadIdx.x;
  if (tid < 16) curs[tid] = bbase[blockIdx.x * 16 + tid];
  __syncthreads();
  if (tid < GR) {
    int row = blockIdx.x * GR + tid;
    int ee = rinfo_e[row];
    int e0 = ee & 255, e1 = (ee >> 8) & 255;
    int p0 = atomicAdd(&curs[e0], 1);           // LDS atomic
    rowidx[p0] = row; wgt[p0] = rinfo_w[row * 2 + 0];
    int p1 = atomicAdd(&curs[8 + e1], 1);
    rowidx[p1] = row; wgt[p1] = rinfo_w[row * 2 + 1];
  }
}

// src fp32 [E][R][C] -> dst bf16 [E][C][R]
__global__ void transpose_kernel(const float* __restrict__ src,
                                 unsigned short* __restrict__ dst, int R, int C) {
  __shared__ float tbuf[32][33];
  int e = blockIdx.z;
  int c0 = blockIdx.x * 32, r0 = blockIdx.y * 32;
  int tx = threadIdx.x, ty = threadIdx.y;
  const float* s = src + (size_t)e * R * C;
  unsigned short* d = dst + (size_t)e * R * C;
  for (int yy = ty; yy < 32; yy += 8)
    tbuf[yy][tx] = s[(size_t)(r0 + yy) * C + c0 + tx];
  __syncthreads();
  for (int yy = ty; yy < 32; yy += 8)
    d[(size_t)(c0 + yy) * R + r0 + tx] = f2bf(tbuf[tx][yy]);
}

// ---------------- grouped GEMM1: h = gelu(Xg @ w1[e] + b1[e]) ----------------
__global__ __launch_bounds__(256) void gemm1_kernel(
    const float* __restrict__ x,
    const unsigned short* __restrict__ w1t,   // [E][H][D] bf16
    const float* __restrict__ b1,             // [E][H] fp32
    const int* __restrict__ cnt,
    const int* __restrict__ rowidx,
    unsigned short* __restrict__ hbuf,        // [*][256] bf16
    int g0, int g1, int hbase) {
  __shared__ unsigned short As[128][72];
  __shared__ unsigned short Bs[128][72];
  int t = blockIdx.x, g = -1, lt = 0;
#pragma unroll 1
  for (int gg = g0; gg < g1; gg++) {
    int nt = (cnt[gg] + 127) >> 7;
    if (t < nt) { g = gg; lt = t; break; }
    t -= nt;
  }
  if (g < 0) return;
  const int* offs = cnt + 32;
  int m0 = offs[g] + lt * 128;
  int mEnd = offs[g] + cnt[g];
  int e = g & 7;
  int n0 = blockIdx.y * 128;
  const unsigned short* Bsrc = w1t + (size_t)e * HH * DD + (size_t)n0 * DD;
  int tid = threadIdx.x, lane = tid & 63, wv = tid >> 6;
  int wr = (wv >> 1) * 64, wc = (wv & 1) * 64;
  int lm = lane & 15, q = lane >> 4;
  floatx4 acc[4][4];
  floatx4 zero = {0.f, 0.f, 0.f, 0.f};
#pragma unroll
  for (int i = 0; i < 4; i++)
#pragma unroll
    for (int j = 0; j < 4; j++) acc[i][j] = zero;
  int sr = tid >> 3;
  int sc = (tid & 7) * 8;
  int grows[4];
#pragma unroll
  for (int it = 0; it < 4; it++) {
    int pos = m0 + it * 32 + sr;
    grows[it] = (pos < mEnd) ? rowidx[pos] : -1;
  }
#pragma unroll 1
  for (int k0 = 0; k0 < DD; k0 += 64) {
#pragma unroll
    for (int it = 0; it < 4; it++) {
      int r = it * 32 + sr;
      uint4 av = {0u, 0u, 0u, 0u};
      if (grows[it] >= 0) {
        const float* srcp = x + (size_t)grows[it] * DD + k0 + sc;
        float4 f0 = *(const float4*)srcp;
        float4 f1 = *(const float4*)(srcp + 4);
        av.x = pack2(f0.x, f0.y); av.y = pack2(f0.z, f0.w);
        av.z = pack2(f1.x, f1.y); av.w = pack2(f1.z, f1.w);
      }
      *(uint4*)&As[r][sc] = av;
      *(uint4*)&Bs[r][sc] = *(const uint4*)(Bsrc + (size_t)r * DD + k0 + sc);
    }
    __syncthreads();
#pragma unroll
    for (int ks = 0; ks < 2; ks++) {
      short8 a[4], b[4];
#pragma unroll
      for (int i = 0; i < 4; i++)
        a[i] = *(const short8*)&As[wr + i * 16 + lm][ks * 32 + q * 8];
#pragma unroll
      for (int j = 0; j < 4; j++)
        b[j] = *(const short8*)&Bs[wc + j * 16 + lm][ks * 32 + q * 8];
#pragma unroll
      for (int i = 0; i < 4; i++)
#pragma unroll
        for (int j = 0; j < 4; j++)
          acc[i][j] = __builtin_amdgcn_mfma_f32_16x16x32_bf16(a[i], b[j], acc[i][j], 0, 0, 0);
    }
    __syncthreads();
  }
#pragma unroll
  for (int i = 0; i < 4; i++) {
#pragma unroll
    for (int r = 0; r < 4; r++) {
      int row = wr + i * 16 + q * 4 + r;
      int pos = m0 + row;
      if (pos < mEnd) {
#pragma unroll
        for (int j = 0; j < 4; j++) {
          int col = n0 + wc + j * 16 + lm;
          float v = acc[i][j][r] + b1[e * HH + col];
          v = 0.5f * v * (1.f + erff(v * 0.70710678118654752f));  // exact GELU
          hbuf[(size_t)(pos - hbase) * HH + col] = f2bf(v);
        }
      }
    }
  }
}

// ---------------- grouped GEMM2: out (+)= w * (h @ w2[e] + b2[e]) ----------------
__global__ __launch_bounds__(256) void gemm2_kernel(
    const unsigned short* __restrict__ hbuf,
    const unsigned short* __restrict__ w2t,   // [E][D][H] bf16
    const float* __restrict__ b2,             // [E][D] fp32
    const int* __restrict__ cnt,
    const int* __restrict__ rowidx,
    const float* __restrict__ wgt,
    float* __restrict__ out,
    int phase, int hbase) {
  __shared__ unsigned short As[128][72];
  __shared__ unsigned short Bs[128][72];
  int t = blockIdx.x, g = -1, lt = 0;
#pragma unroll 1
  for (int gg = 0; gg < 8; gg++) {
    int G = phase * 8 + gg;
    int nt = (cnt[G] + 127) >> 7;
    if (t < nt) { g = G; lt = t; break; }
    t -= nt;
  }
  if (g < 0) return;
  const int* offs = cnt + 32;
  int m0 = offs[g] + lt * 128;
  int mEnd = offs[g] + cnt[g];
  int e = g & 7;
  int n0 = blockIdx.y * 128;
  const unsigned short* Bsrc = w2t + (size_t)e * DD * HH + (size_t)n0 * HH;
  int tid = threadIdx.x, lane = tid & 63, wv = tid >> 6;
  int wr = (wv >> 1) * 64, wc = (wv & 1) * 64;
  int lm = lane & 15, q = lane >> 4;
  floatx4 acc[4][4];
  floatx4 zero = {0.f, 0.f, 0.f, 0.f};
#pragma unroll
  for (int i = 0; i < 4; i++)
#pragma unroll
    for (int j = 0; j < 4; j++) acc[i][j] = zero;
  int sr = tid >> 3;
  int sc = (tid & 7) * 8;
#pragma unroll 1
  for (int k0 = 0; k0 < HH; k0 += 64) {
#pragma unroll
    for (int it = 0; it < 4; it++) {
      int r = it * 32 + sr;
      int pos = m0 + r;
      uint4 av = {0u, 0u, 0u, 0u};
      if (pos < mEnd)
        av = *(const uint4*)(hbuf + (size_t)(pos - hbase) * HH + k0 + sc);
      *(uint4*)&As[r][sc] = av;
      *(uint4*)&Bs[r][sc] = *(const uint4*)(Bsrc + (size_t)r * HH + k0 + sc);
    }
    __syncthreads();
#pragma unroll
    for (int ks = 0; ks < 2; ks++) {
      short8 a[4], b[4];
#pragma unroll
      for (int i = 0; i < 4; i++)
        a[i] = *(const short8*)&As[wr + i * 16 + lm][ks * 32 + q * 8];
#pragma unroll
      for (int j = 0; j < 4; j++)
        b[j] = *(const short8*)&Bs[wc + j * 16 + lm][ks * 32 + q * 8];
#pragma unroll
      for (int i = 0; i < 4; i++)
#pragma unroll
        for (int j = 0; j < 4; j++)
          acc[i][j] = __builtin_amdgcn_mfma_f32_16x16x32_bf16(a[i], b[j], acc[i][j], 0, 0, 0);
    }
    __syncthreads();
  }
#pragma unroll
  for (int i = 0; i < 4; i++) {
#pragma unroll
    for (int r = 0; r < 4; r++) {
      int row = wr + i * 16 + q * 4 + r;
      int pos = m0 + row;
      if (pos < mEnd) {
        int grow = rowidx[pos];
        float wgain = wgt[pos];
#pragma unroll
        for (int j = 0; j < 4; j++) {
          int col = n0 + wc + j * 16 + lm;
          float v = (acc[i][j][r] + b2[e * DD + col]) * wgain;
          size_t oidx = (size_t)grow * DD + col;
          if (phase) v += out[oidx];
          out[oidx] = v;
        }
      }
    }
  }
}

extern "C" void kernel_launch(void* const* d_in, const int* in_sizes, int n_in,
                              void* d_out, int out_size, void* d_ws, size_t ws_size,
                              hipStream_t stream) {
  (void)in_sizes; (void)n_in; (void)out_size;
  const float* x      = (const float*)d_in[0];
  const float* gate_w = (const float*)d_in[1];
  const float* gate_b = (const float*)d_in[2];
  const float* w1     = (const float*)d_in[3];
  const float* b1     = (const float*)d_in[4];
  const float* w2     = (const float*)d_in[5];
  const float* b2     = (const float*)d_in[6];
  float* out = (float*)d_out;

  char* w = (char*)d_ws;
  int* cnt            = (int*)(w);                 // 48 ints: counts / (unused) / offsets
  int* rinfo_e        = (int*)(w + 256);           // [16384]
  float* rinfo_w      = (float*)(w + 65792);       // [32768]
  int* bhist          = (int*)(w + 196864);        // [512][16]
  int* bbase          = (int*)(w + 229632);        // [512][16]
  int* rowidx         = (int*)(w + 262400);        // [32768]
  float* wgt          = (float*)(w + 393472);      // [32768]
  unsigned short* w1t = (unsigned short*)(w + 524544);            // 4 MB bf16
  unsigned short* w2t = (unsigned short*)(w + 524544 + 4194304);  // 4 MB bf16
  unsigned short* hbuf= (unsigned short*)(w + 524544 + 8388608);  // 8 or 16 MB bf16
  bool fused = ws_size >= (size_t)(524544 + 8388608 + 16777216);

  transpose_kernel<<<dim3(HH / 32, DD / 32, EE), dim3(32, 8), 0, stream>>>(w1, w1t, DD, HH);
  transpose_kernel<<<dim3(DD / 32, HH / 32, EE), dim3(32, 8), 0, stream>>>(w2, w2t, HH, DD);
  gating_kernel<<<GB, 256, 0, stream>>>(x, gate_w, gate_b, rinfo_e, rinfo_w, bhist);
  scan_kernel<<<1, 256, 0, stream>>>(bhist, cnt, bbase);
  scatter_kernel<<<GB, 64, 0, stream>>>(rinfo_e, rinfo_w, bbase, rowidx, wgt);
  if (fused) {
    gemm1_kernel<<<dim3(272, 2), 256, 0, stream>>>(x, w1t, b1, cnt, rowidx, hbuf, 0, 16, 0);
    gemm2_kernel<<<dim3(136, 8), 256, 0, stream>>>(hbuf, w2t, b2, cnt, rowidx, wgt, out, 0, 0);
    gemm2_kernel<<<dim3(136, 8), 256, 0, stream>>>(hbuf, w2t, b2, cnt, rowidx, wgt, out, 1, 0);
  } else {
    gemm1_kernel<<<dim3(136, 2), 256, 0, stream>>>(x, w1t, b1, cnt, rowidx, hbuf, 0, 8, 0);
    gemm2_kernel<<<dim3(136, 8), 256, 0, stream>>>(hbuf, w2t, b2, cnt, rowidx, wgt, out, 0, 0);
    gemm1_kernel<<<dim3(136, 2), 256, 0, stream>>>(x, w1t, b1, cnt, rowidx, hbuf, 8, 16, 16384);
    gemm2_kernel<<<dim3(136, 8), 256, 0, stream>>>(hbuf, w2t, b2, cnt, rowidx, wgt, out, 1, 16384);
  }
}

// Round 4
// 398.431 us; speedup vs baseline: 2.2256x; 1.0906x over previous
//
#include <hip/hip_runtime.h>
#include <stdint.h>

#define BN 16384
#define DD 1024
#define HH 256
#define EE 8
#define GB 512   // gating blocks
#define GR 32    // rows per gating block

typedef __attribute__((ext_vector_type(8))) short short8;
typedef __attribute__((ext_vector_type(4))) float floatx4;

__device__ __forceinline__ unsigned short f2bf(float f) {
  union { float f; unsigned int i; } v; v.f = f;
  unsigned int x = v.i;
  x += 0x7fffu + ((x >> 16) & 1u);  // RTNE
  return (unsigned short)(x >> 16);
}
__device__ __forceinline__ unsigned int pack2(float a, float b) {
  return (unsigned int)f2bf(a) | ((unsigned int)f2bf(b) << 16);
}
// async 16B/lane global->LDS DMA; lds dst must be wave-uniform base (+lane*16 by HW)
__device__ __forceinline__ void async16(const unsigned short* g, unsigned short* l) {
  __builtin_amdgcn_global_load_lds(
      (const __attribute__((address_space(1))) void*)g,
      (__attribute__((address_space(3))) void*)l, 16, 0, 0);
}

// ---------------- convert x fp32 -> bf16 ----------------
__global__ __launch_bounds__(256) void convert_kernel(const float* __restrict__ x,
                                                      unsigned short* __restrict__ xb) {
  size_t idx = ((size_t)blockIdx.x * 256 + threadIdx.x) * 8;
  float4 f0 = *(const float4*)(x + idx);
  float4 f1 = *(const float4*)(x + idx + 4);
  uint4 o;
  o.x = pack2(f0.x, f0.y); o.y = pack2(f0.z, f0.w);
  o.z = pack2(f1.x, f1.y); o.w = pack2(f1.z, f1.w);
  *(uint4*)(xb + idx) = o;
}

// ---------------- gating: fp32 logits -> top2 -> rinfo + per-block histogram ----------------
__global__ __launch_bounds__(256) void gating_kernel(
    const float* __restrict__ x,
    const float* __restrict__ gate_w,
    const float* __restrict__ gate_b,
    int* __restrict__ rinfo_e, float* __restrict__ rinfo_w,
    int* __restrict__ bhist) {
  __shared__ int hist[16];
  int tid = threadIdx.x;
  if (tid < 16) hist[tid] = 0;
  __syncthreads();
  int lane = tid & 63, wv = tid >> 6;
#pragma unroll 1
  for (int it = 0; it < GR / 4; it++) {
    int row = blockIdx.x * GR + it * 4 + wv;
    const float4* xr4 = (const float4*)(x + (size_t)row * DD);
    float acc[EE];
#pragma unroll
    for (int e = 0; e < EE; e++) acc[e] = 0.f;
#pragma unroll
    for (int i = 0; i < 4; i++) {
      int d4 = lane + i * 64;  // float4 index
      float4 xv = xr4[d4];
      const float4* gp = (const float4*)gate_w + (size_t)d4 * 8;
      float xs[4] = {xv.x, xv.y, xv.z, xv.w};
#pragma unroll
      for (int j = 0; j < 4; j++) {
        float4 glo = gp[2 * j], ghi = gp[2 * j + 1];
        acc[0] += xs[j] * glo.x; acc[1] += xs[j] * glo.y;
        acc[2] += xs[j] * glo.z; acc[3] += xs[j] * glo.w;
        acc[4] += xs[j] * ghi.x; acc[5] += xs[j] * ghi.y;
        acc[6] += xs[j] * ghi.z; acc[7] += xs[j] * ghi.w;
      }
    }
#pragma unroll
    for (int s = 1; s < 64; s <<= 1) {
#pragma unroll
      for (int e = 0; e < EE; e++) acc[e] += __shfl_xor(acc[e], s, 64);
    }
    if (lane == 0) {
      float lg[EE];
#pragma unroll
      for (int e = 0; e < EE; e++) lg[e] = acc[e] + gate_b[e];
      int i1 = 0;
      for (int e = 1; e < EE; e++) if (lg[e] > lg[i1]) i1 = e;
      int i2 = (i1 == 0) ? 1 : 0;
      for (int e = 0; e < EE; e++) if (e != i1 && lg[e] > lg[i2]) i2 = e;
      float wA = 1.f / (1.f + __expf(lg[i2] - lg[i1]));  // p1/(p1+p2), arg <= 0
      float wB = 1.f - wA;
      rinfo_e[row] = i1 | (i2 << 8);
      rinfo_w[row * 2 + 0] = wA;
      rinfo_w[row * 2 + 1] = wB;
      atomicAdd(&hist[i1], 1);      // LDS atomics only
      atomicAdd(&hist[8 + i2], 1);
    }
  }
  __syncthreads();
  if (tid < 16) bhist[blockIdx.x * 16 + tid] = hist[tid];
}

// ---------------- scan: totals, group offsets, per-block bases (deterministic) ----------------
__global__ __launch_bounds__(256) void scan_kernel(
    const int* __restrict__ bhist, int* __restrict__ cnt, int* __restrict__ bbase) {
  __shared__ int cs[16][16];
  __shared__ int ofs[16];
  int tid = threadIdx.x;
  int g = tid & 15, c = tid >> 4;
  int s = 0;
#pragma unroll 1
  for (int b = c * 32; b < c * 32 + 32; b++) s += bhist[b * 16 + g];
  cs[c][g] = s;
  __syncthreads();
  if (tid == 0) {
    int run = 0;
    for (int gg = 0; gg < 16; gg++) {
      int tot = 0;
      for (int cc = 0; cc < 16; cc++) tot += cs[cc][gg];
      cnt[gg] = tot;
      cnt[16 + gg] = 0;
      cnt[32 + gg] = run;
      ofs[gg] = run;
      run += tot;
    }
  }
  __syncthreads();
  if (tid < 16) {
    int run = ofs[tid];
#pragma unroll 1
    for (int cc = 0; cc < 16; cc++) { int t = cs[cc][tid]; cs[cc][tid] = run; run += t; }
  }
  __syncthreads();
  int run = cs[c][g];
#pragma unroll 1
  for (int b = c * 32; b < c * 32 + 32; b++) {
    bbase[b * 16 + g] = run;
    run += bhist[b * 16 + g];
  }
}

// ---------------- scatter ----------------
__global__ __launch_bounds__(64) void scatter_kernel(
    const int* __restrict__ rinfo_e, const float* __restrict__ rinfo_w,
    const int* __restrict__ bbase,
    int* __restrict__ rowidx, float* __restrict__ wgt) {
  __shared__ int curs[16];
  int tid = threadIdx.x;
  if (tid < 16) curs[tid] = bbase[blockIdx.x * 16 + tid];
  __syncthreads();
  if (tid < GR) {
    int row = blockIdx.x * GR + tid;
    int ee = rinfo_e[row];
    int e0 = ee & 255, e1 = (ee >> 8) & 255;
    int p0 = atomicAdd(&curs[e0], 1);
    rowidx[p0] = row; wgt[p0] = rinfo_w[row * 2 + 0];
    int p1 = atomicAdd(&curs[8 + e1], 1);
    rowidx[p1] = row; wgt[p1] = rinfo_w[row * 2 + 1];
  }
}

// src fp32 [E][R][C] -> dst bf16 [E][C][R]
__global__ void transpose_kernel(const float* __restrict__ src,
                                 unsigned short* __restrict__ dst, int R, int C) {
  __shared__ float tbuf[32][33];
  int e = blockIdx.z;
  int c0 = blockIdx.x * 32, r0 = blockIdx.y * 32;
  int tx = threadIdx.x, ty = threadIdx.y;
  const float* s = src + (size_t)e * R * C;
  unsigned short* d = dst + (size_t)e * R * C;
  for (int yy = ty; yy < 32; yy += 8)
    tbuf[yy][tx] = s[(size_t)(r0 + yy) * C + c0 + tx];
  __syncthreads();
  for (int yy = ty; yy < 32; yy += 8)
    d[(size_t)(c0 + yy) * R + r0 + tx] = f2bf(tbuf[tx][yy]);
}

// ---------------- grouped GEMM1: h = gelu(Xg @ w1[e] + b1[e]) ----------------
// 128x128 tile, unpadded LDS, async global->LDS staging (m97 structure)
template <bool ASYNC_A>
__global__ __launch_bounds__(256) void gemm1_kernel(
    const unsigned short* __restrict__ xb,    // bf16 [B][D] (ASYNC_A)
    const float* __restrict__ x,              // fp32 [B][D] (!ASYNC_A)
    const unsigned short* __restrict__ w1t,   // [E][H][D] bf16
    const float* __restrict__ b1,             // [E][H] fp32
    const int* __restrict__ cnt,
    const int* __restrict__ rowidx,
    unsigned short* __restrict__ hbuf,        // [*][256] bf16
    int g0, int g1, int hbase) {
  __shared__ unsigned short As[128 * 64];
  __shared__ unsigned short Bs[128 * 64];
  int t = blockIdx.x, g = -1, lt = 0;
#pragma unroll 1
  for (int gg = g0; gg < g1; gg++) {
    int nt = (cnt[gg] + 127) >> 7;
    if (t < nt) { g = gg; lt = t; break; }
    t -= nt;
  }
  if (g < 0) return;
  const int* offs = cnt + 32;
  int m0 = offs[g] + lt * 128;
  int mEnd = offs[g] + cnt[g];
  int e = g & 7;
  int n0 = blockIdx.y * 128;
  const unsigned short* Bsrc = w1t + (size_t)e * HH * DD + (size_t)n0 * DD;
  int tid = threadIdx.x, lane = tid & 63, wv = tid >> 6;
  int wr = (wv >> 1) * 64, wc = (wv & 1) * 64;
  int lm = lane & 15, q = lane >> 4;
  floatx4 acc[4][4];
  floatx4 zero = {0.f, 0.f, 0.f, 0.f};
#pragma unroll
  for (int i = 0; i < 4; i++)
#pragma unroll
    for (int j = 0; j < 4; j++) acc[i][j] = zero;
  int srow = tid >> 3;           // 0..31
  int scol = (tid & 7) * 8;      // elems
  const unsigned short* gA[4];
  const float* gAf[4];
  const unsigned short* gBp[4];
#pragma unroll
  for (int i = 0; i < 4; i++) {
    int pos = m0 + i * 32 + srow;
    int grow = rowidx[pos < mEnd ? pos : m0];  // clamp: data discarded at epilogue
    if (ASYNC_A) gA[i] = xb + (size_t)grow * DD + scol;
    else         gAf[i] = x + (size_t)grow * DD + scol;
    gBp[i] = Bsrc + (size_t)(i * 32 + srow) * DD + scol;
  }
  unsigned short* AsW = As + wv * 512;   // wave-uniform LDS bases
  unsigned short* BsW = Bs + wv * 512;
#pragma unroll 1
  for (int k0 = 0; k0 < DD; k0 += 64) {
    if (ASYNC_A) {
#pragma unroll
      for (int i = 0; i < 4; i++) async16(gA[i], AsW + i * 2048);
#pragma unroll
      for (int i = 0; i < 4; i++) gA[i] += 64;
    } else {
#pragma unroll
      for (int i = 0; i < 4; i++) {
        float4 f0 = *(const float4*)gAf[i];
        float4 f1 = *(const float4*)(gAf[i] + 4);
        gAf[i] += 64;
        uint4 av;
        av.x = pack2(f0.x, f0.y); av.y = pack2(f0.z, f0.w);
        av.z = pack2(f1.x, f1.y); av.w = pack2(f1.z, f1.w);
        *(uint4*)&As[(i * 32 + srow) * 64 + scol] = av;
      }
    }
#pragma unroll
    for (int i = 0; i < 4; i++) async16(gBp[i], BsW + i * 2048);
#pragma unroll
    for (int i = 0; i < 4; i++) gBp[i] += 64;
    __syncthreads();
#pragma unroll
    for (int ks = 0; ks < 2; ks++) {
      short8 a[4], b[4];
#pragma unroll
      for (int i = 0; i < 4; i++)
        a[i] = *(const short8*)&As[(wr + i * 16 + lm) * 64 + ks * 32 + q * 8];
#pragma unroll
      for (int j = 0; j < 4; j++)
        b[j] = *(const short8*)&Bs[(wc + j * 16 + lm) * 64 + ks * 32 + q * 8];
#pragma unroll
      for (int i = 0; i < 4; i++)
#pragma unroll
        for (int j = 0; j < 4; j++)
          acc[i][j] = __builtin_amdgcn_mfma_f32_16x16x32_bf16(a[i], b[j], acc[i][j], 0, 0, 0);
    }
    __syncthreads();
  }
#pragma unroll
  for (int i = 0; i < 4; i++) {
#pragma unroll
    for (int r = 0; r < 4; r++) {
      int row = wr + i * 16 + q * 4 + r;
      int pos = m0 + row;
      if (pos < mEnd) {
#pragma unroll
        for (int j = 0; j < 4; j++) {
          int col = n0 + wc + j * 16 + lm;
          float v = acc[i][j][r] + b1[e * HH + col];
          v = 0.5f * v * (1.f + erff(v * 0.70710678118654752f));  // exact GELU
          hbuf[(size_t)(pos - hbase) * HH + col] = f2bf(v);
        }
      }
    }
  }
}

// ---------------- grouped GEMM2: out (+)= w * (h @ w2[e] + b2[e]) ----------------
__global__ __launch_bounds__(256) void gemm2_kernel(
    const unsigned short* __restrict__ hbuf,
    const unsigned short* __restrict__ w2t,   // [E][D][H] bf16
    const float* __restrict__ b2,             // [E][D] fp32
    const int* __restrict__ cnt,
    const int* __restrict__ rowidx,
    const float* __restrict__ wgt,
    float* __restrict__ out,
    int phase, int hbase) {
  __shared__ unsigned short As[128 * 64];
  __shared__ unsigned short Bs[128 * 64];
  int t = blockIdx.x, g = -1, lt = 0;
#pragma unroll 1
  for (int gg = 0; gg < 8; gg++) {
    int G = phase * 8 + gg;
    int nt = (cnt[G] + 127) >> 7;
    if (t < nt) { g = G; lt = t; break; }
    t -= nt;
  }
  if (g < 0) return;
  const int* offs = cnt + 32;
  int m0 = offs[g] + lt * 128;
  int mEnd = offs[g] + cnt[g];
  int e = g & 7;
  int n0 = blockIdx.y * 128;
  const unsigned short* Bsrc = w2t + (size_t)e * DD * HH + (size_t)n0 * HH;
  int tid = threadIdx.x, lane = tid & 63, wv = tid >> 6;
  int wr = (wv >> 1) * 64, wc = (wv & 1) * 64;
  int lm = lane & 15, q = lane >> 4;
  floatx4 acc[4][4];
  floatx4 zero = {0.f, 0.f, 0.f, 0.f};
#pragma unroll
  for (int i = 0; i < 4; i++)
#pragma unroll
    for (int j = 0; j < 4; j++) acc[i][j] = zero;
  int srow = tid >> 3;
  int scol = (tid & 7) * 8;
  const unsigned short* gA[4];
  const unsigned short* gBp[4];
#pragma unroll
  for (int i = 0; i < 4; i++) {
    int pos = m0 + i * 32 + srow;
    int posc = (pos < mEnd) ? pos : m0;       // clamp: discarded at epilogue
    gA[i] = hbuf + (size_t)(posc - hbase) * HH + scol;
    gBp[i] = Bsrc + (size_t)(i * 32 + srow) * HH + scol;
  }
  unsigned short* AsW = As + wv * 512;
  unsigned short* BsW = Bs + wv * 512;
#pragma unroll 1
  for (int k0 = 0; k0 < HH; k0 += 64) {
#pragma unroll
    for (int i = 0; i < 4; i++) async16(gA[i], AsW + i * 2048);
#pragma unroll
    for (int i = 0; i < 4; i++) async16(gBp[i], BsW + i * 2048);
#pragma unroll
    for (int i = 0; i < 4; i++) { gA[i] += 64; gBp[i] += 64; }
    __syncthreads();
#pragma unroll
    for (int ks = 0; ks < 2; ks++) {
      short8 a[4], b[4];
#pragma unroll
      for (int i = 0; i < 4; i++)
        a[i] = *(const short8*)&As[(wr + i * 16 + lm) * 64 + ks * 32 + q * 8];
#pragma unroll
      for (int j = 0; j < 4; j++)
        b[j] = *(const short8*)&Bs[(wc + j * 16 + lm) * 64 + ks * 32 + q * 8];
#pragma unroll
      for (int i = 0; i < 4; i++)
#pragma unroll
        for (int j = 0; j < 4; j++)
          acc[i][j] = __builtin_amdgcn_mfma_f32_16x16x32_bf16(a[i], b[j], acc[i][j], 0, 0, 0);
    }
    __syncthreads();
  }
#pragma unroll
  for (int i = 0; i < 4; i++) {
#pragma unroll
    for (int r = 0; r < 4; r++) {
      int row = wr + i * 16 + q * 4 + r;
      int pos = m0 + row;
      if (pos < mEnd) {
        int grow = rowidx[pos];
        float wgain = wgt[pos];
#pragma unroll
        for (int j = 0; j < 4; j++) {
          int col = n0 + wc + j * 16 + lm;
          float v = (acc[i][j][r] + b2[e * DD + col]) * wgain;
          size_t oidx = (size_t)grow * DD + col;
          if (phase) v += out[oidx];
          out[oidx] = v;
        }
      }
    }
  }
}

extern "C" void kernel_launch(void* const* d_in, const int* in_sizes, int n_in,
                              void* d_out, int out_size, void* d_ws, size_t ws_size,
                              hipStream_t stream) {
  (void)in_sizes; (void)n_in; (void)out_size;
  const float* x      = (const float*)d_in[0];
  const float* gate_w = (const float*)d_in[1];
  const float* gate_b = (const float*)d_in[2];
  const float* w1     = (const float*)d_in[3];
  const float* b1     = (const float*)d_in[4];
  const float* w2     = (const float*)d_in[5];
  const float* b2     = (const float*)d_in[6];
  float* out = (float*)d_out;

  char* w = (char*)d_ws;
  int* cnt            = (int*)(w);                 // 48 ints
  int* rinfo_e        = (int*)(w + 256);           // [16384]
  float* rinfo_w      = (float*)(w + 65792);       // [32768]
  int* bhist          = (int*)(w + 196864);        // [512][16]
  int* bbase          = (int*)(w + 229632);        // [512][16]
  int* rowidx         = (int*)(w + 262400);        // [32768]
  float* wgt          = (float*)(w + 393472);      // [32768]
  unsigned short* w1t = (unsigned short*)(w + 524544);             // 4 MB bf16
  unsigned short* w2t = (unsigned short*)(w + 4718848);            // 4 MB bf16
  unsigned short* hbuf= (unsigned short*)(w + 8913152);            // 8/16 MB bf16
  unsigned short* xb  = (unsigned short*)(w + 25690368);           // 32 MB bf16
  bool fused  = ws_size >= (size_t)25690368;
  bool use_xb = ws_size >= (size_t)(25690368 + 33554432);

  transpose_kernel<<<dim3(HH / 32, DD / 32, EE), dim3(32, 8), 0, stream>>>(w1, w1t, DD, HH);
  transpose_kernel<<<dim3(DD / 32, HH / 32, EE), dim3(32, 8), 0, stream>>>(w2, w2t, HH, DD);
  gating_kernel<<<GB, 256, 0, stream>>>(x, gate_w, gate_b, rinfo_e, rinfo_w, bhist);
  scan_kernel<<<1, 256, 0, stream>>>(bhist, cnt, bbase);
  scatter_kernel<<<GB, 64, 0, stream>>>(rinfo_e, rinfo_w, bbase, rowidx, wgt);
  if (use_xb) {
    convert_kernel<<<BN * DD / (256 * 8), 256, 0, stream>>>(x, xb);
    gemm1_kernel<true><<<dim3(272, 2), 256, 0, stream>>>(xb, x, w1t, b1, cnt, rowidx, hbuf, 0, 16, 0);
    gemm2_kernel<<<dim3(136, 8), 256, 0, stream>>>(hbuf, w2t, b2, cnt, rowidx, wgt, out, 0, 0);
    gemm2_kernel<<<dim3(136, 8), 256, 0, stream>>>(hbuf, w2t, b2, cnt, rowidx, wgt, out, 1, 0);
  } else if (fused) {
    gemm1_kernel<false><<<dim3(272, 2), 256, 0, stream>>>(nullptr, x, w1t, b1, cnt, rowidx, hbuf, 0, 16, 0);
    gemm2_kernel<<<dim3(136, 8), 256, 0, stream>>>(hbuf, w2t, b2, cnt, rowidx, wgt, out, 0, 0);
    gemm2_kernel<<<dim3(136, 8), 256, 0, stream>>>(hbuf, w2t, b2, cnt, rowidx, wgt, out, 1, 0);
  } else {
    gemm1_kernel<false><<<dim3(136, 2), 256, 0, stream>>>(nullptr, x, w1t, b1, cnt, rowidx, hbuf, 0, 8, 0);
    gemm2_kernel<<<dim3(136, 8), 256, 0, stream>>>(hbuf, w2t, b2, cnt, rowidx, wgt, out, 0, 0);
    gemm1_kernel<false><<<dim3(136, 2), 256, 0, stream>>>(nullptr, x, w1t, b1, cnt, rowidx, hbuf, 8, 16, 16384);
    gemm2_kernel<<<dim3(136, 8), 256, 0, stream>>>(hbuf, w2t, b2, cnt, rowidx, wgt, out, 1, 16384);
  }
}